// Round 5
// baseline (278.431 us; speedup 1.0000x reference)
//
#include <hip/hip_runtime.h>
#include <math.h>

// Problem constants: B=8, spatial 64x64 (HW=4096), C_mid=256, C=128, N=9 taps.
// All inputs/outputs are float32.
typedef const float* fp;
typedef __attribute__((ext_vector_type(8))) short short8;   // 8 bf16 = 4 VGPRs (MFMA A/B frag)
typedef __attribute__((ext_vector_type(4))) float f32x4;    // MFMA C/D frag

__device__ __forceinline__ unsigned short f2bf(float f){    // RTNE float->bf16
    unsigned u = __float_as_uint(f);
    u += 0x7fff + ((u >> 16) & 1);
    return (unsigned short)(u >> 16);
}

// ---------------- K0: merged prep — Wbf[n][o][c] bf16, Wpm[n][32q][128c] bf16, Wpwt[c][128o] f32
__global__ __launch_bounds__(256) void k_prep(fp dcn_w, fp pw, fp mw, fp pww,
                                              unsigned short* Wbf, unsigned short* Wpm, float* Wpwt){
    int i = blockIdx.x*256 + threadIdx.x;       // 217088 = 848 blocks
    if(i < 147456){
        int c = i & 127, o = (i >> 7) & 127, n = i >> 14;
        Wbf[i] = f2bf(dcn_w[o*1152 + c*9 + n]);
    } else if(i < 184320){
        int j = i - 147456;
        int c = j & 127, q = (j >> 7) & 31, n = j >> 12;
        float v = 0.f;
        if(q < 18)      v = pw[q*1152 + c*9 + n];
        else if(q < 27) v = mw[(q-18)*1152 + c*9 + n];
        Wpm[j] = f2bf(v);
    } else {
        int j = i - 184320;                     // 32768
        int o = j & 127, c = j >> 7;
        Wpwt[c*128 + o] = pww[o*256 + c];
    }
}

// ---------------- K1: fused upsample+concat+depthwise256 -> Bo (8,256,64,64)
// float4 staging (x2 path) + float4 conv epilogue.
__global__ __launch_bounds__(256) void k_updw256(fp x1, fp x2, fp w, fp bias, float* Bo){
    __shared__ float sA[66*68 + 4];
    int bid = blockIdx.x;
    int c = bid & 255, b = bid >> 8;
    int tid = threadIdx.x;
    // zero halo ring (rows 0/65, cols 0/65) + pad
    for(int j = tid; j < 264; j += 256){
        int idx;
        if(j < 66)       idx = j;
        else if(j < 132) idx = 65*68 + (j-66);
        else if(j < 196) idx = (j-132+1)*68;
        else if(j < 260) idx = (j-196+1)*68 + 65;
        else             idx = 66*68 + (j-260);
        sA[idx] = 0.f;
    }
    if(c < 128){
        const float* src = x2 + ((size_t)(b*128+c)<<12);
        for(int j = tid; j < 1024; j += 256){       // 64 rows x 16 float4
            int yy = j >> 4, x4 = (j & 15) << 2;
            float4 v = *(const float4*)&src[(yy<<6) + x4];
            float* d = &sA[(yy+1)*68 + x4 + 1];
            d[0]=v.x; d[1]=v.y; d[2]=v.z; d[3]=v.w;
        }
    } else {
        int cc = c - 128;
        fp src = x1 + ((b*128+cc)<<10);
        const float s = 31.0f/63.0f;
        for(int j = tid; j < 4096; j += 256){
            int yy = j >> 6, xx = j & 63;
            float fy = yy*s, fx = xx*s;
            int iy = (int)fy; if (iy > 30) iy = 30;
            int ix = (int)fx; if (ix > 30) ix = 30;
            float ty = fy - (float)iy, tx = fx - (float)ix;
            float v00 = src[iy*32+ix],     v01 = src[iy*32+ix+1];
            float v10 = src[(iy+1)*32+ix], v11 = src[(iy+1)*32+ix+1];
            sA[(yy+1)*68 + xx + 1] =
                (v00*(1.f-ty)+v10*ty)*(1.f-tx) + (v01*(1.f-ty)+v11*ty)*tx;
        }
    }
    __syncthreads();
    float w0=w[c*9+0], w1=w[c*9+1], w2=w[c*9+2];
    float w3=w[c*9+3], w4=w[c*9+4], w5=w[c*9+5];
    float w6=w[c*9+6], w7=w[c*9+7], w8=w[c*9+8];
    float bv = bias[c];
    float* dst = Bo + ((size_t)(b*256+c)<<12);
    for(int j = tid; j < 1024; j += 256){           // 64 rows x 16 float4
        int y = j >> 4, x0 = (j & 15) << 2;
        float a0=bv, a1=bv, a2=bv, a3=bv;
        #pragma unroll
        for(int ky=0; ky<3; ky++){
            const float* rr = &sA[(y+ky)*68 + x0];
            float4 u0 = *(const float4*)&rr[0];
            float2 u1 = *(const float2*)&rr[4];
            float wA = (ky==0)?w0:((ky==1)?w3:w6);
            float wB = (ky==0)?w1:((ky==1)?w4:w7);
            float wC = (ky==0)?w2:((ky==1)?w5:w8);
            a0 += wA*u0.x + wB*u0.y + wC*u0.z;
            a1 += wA*u0.y + wB*u0.z + wC*u0.w;
            a2 += wA*u0.z + wB*u0.w + wC*u1.x;
            a3 += wA*u0.w + wB*u1.x + wC*u1.y;
        }
        *(float4*)&dst[(y<<6)+x0] = make_float4(a0,a1,a2,a3);
    }
}

// ---------------- K3: pointwise 256->128 + bias -> Ccl (channel-last), transposed f32 weights
__global__ __launch_bounds__(256) void k_pw(const float* Bi, fp Wt, fp bias, float* Ccl){
    __shared__ float sIn[256*32];
    int bid = blockIdx.x;                       // 1024
    int b = bid >> 7;
    int pix0 = (bid & 127) << 5;
    int tid = threadIdx.x;
    for(int j = tid; j < 256*32; j += 256){
        int c = j >> 5, p = j & 31;
        sIn[j] = Bi[((b*256 + c)<<12) + pix0 + p];
    }
    __syncthreads();
    int og = tid >> 3, pg = tid & 7;
    int o0 = og*4, p0 = pg*4;
    float acc[4][4];
    #pragma unroll
    for(int i=0;i<4;i++){ float bv=bias[o0+i];
        #pragma unroll
        for(int j=0;j<4;j++) acc[i][j]=bv; }
    for(int c=0;c<256;c++){
        float4 xv = *(const float4*)&sIn[(c<<5)+p0];
        float4 w4 = *(const float4*)&Wt[(c<<7)+o0];
        acc[0][0]+=w4.x*xv.x; acc[0][1]+=w4.x*xv.y; acc[0][2]+=w4.x*xv.z; acc[0][3]+=w4.x*xv.w;
        acc[1][0]+=w4.y*xv.x; acc[1][1]+=w4.y*xv.y; acc[1][2]+=w4.y*xv.z; acc[1][3]+=w4.y*xv.w;
        acc[2][0]+=w4.z*xv.x; acc[2][1]+=w4.z*xv.y; acc[2][2]+=w4.z*xv.z; acc[2][3]+=w4.z*xv.w;
        acc[3][0]+=w4.w*xv.x; acc[3][1]+=w4.w*xv.y; acc[3][2]+=w4.w*xv.z; acc[3][3]+=w4.w*xv.w;
    }
    #pragma unroll
    for(int j=0;j<4;j++){
        int px = pix0 + p0 + j;
        *(float4*)&Ccl[((size_t)(b<<12) + px)*128 + o0] =
            make_float4(acc[0][j],acc[1][j],acc[2][j],acc[3][j]);
    }
}

// ---------------- K4: offset(18)+mask(9, sigmoid) 3x3 conv via bf16 MFMA -> OM (8,27,4096)
__global__ __launch_bounds__(256) void k_offmask(fp Ccl, const unsigned short* Wpm,
                                                 fp pb, fp mb, float* OM){
    __shared__ __align__(16) unsigned short sW[32*136];   // [q][c] bf16
    __shared__ __align__(16) unsigned short sX[64*136];   // [px][c] bf16
    int b = blockIdx.x & 7;
    int y = blockIdx.x >> 3;          // output row
    int pix0 = y << 6;
    int tid = threadIdx.x;
    int lane = tid & 63, wave = tid >> 6;
    int m16 = lane & 15, quad = lane >> 4;
    int wp = wave << 4;               // px-subtile
    const float* cb = Ccl + (size_t)(b<<12)*128;

    // ---- probe: D[m][n]=m*(n+100)
    short8 ap = {0,0,0,0,0,0,0,0}, bpr = {0,0,0,0,0,0,0,0};
    if(quad == 0){
        ap[0]  = (short)f2bf((float)m16);
        bpr[0] = (short)f2bf((float)(m16+100));
    }
    f32x4 dp = {0.f,0.f,0.f,0.f};
    dp = __builtin_amdgcn_mfma_f32_16x16x32_bf16(ap, bpr, dp, 0,0,0);
    bool p1 = true;
    #pragma unroll
    for(int r=0;r<4;r++){
        float expP1 = (float)(quad*4+r) * (float)(m16+100);
        p1 = p1 && (fabsf(dp[r]-expP1) < 0.5f);
    }
    bool swapD = (__ballot(p1) != 0xFFFFFFFFFFFFFFFFull);

    f32x4 acc[2];
    acc[0] = (f32x4){0.f,0.f,0.f,0.f};
    acc[1] = (f32x4){0.f,0.f,0.f,0.f};

    for(int n=0;n<9;n++){
        int ky = n/3, kx = n - ky*3;
        int yy = y + ky - 1;
        bool rowok = (yy>=0 && yy<64);
        const int4* wsrc = (const int4*)(Wpm + (n<<12));
        for(int j=tid; j<512; j+=256){
            int q = j >> 4, cg = j & 15;
            *(int4*)&sW[q*136 + (cg<<3)] = wsrc[j];
        }
        #pragma unroll
        for(int it=0; it<8; it++){
            int e = tid + (it<<8);
            int cg = (e & 31) << 2, px = e >> 5;
            int xx = px + kx - 1;
            float4 v = make_float4(0.f,0.f,0.f,0.f);
            if(rowok && xx>=0 && xx<64)
                v = *(const float4*)&cb[(size_t)((yy<<6)+xx)*128 + cg];
            unsigned long long pk = (unsigned long long)f2bf(v.x)
                | ((unsigned long long)f2bf(v.y)<<16)
                | ((unsigned long long)f2bf(v.z)<<32)
                | ((unsigned long long)f2bf(v.w)<<48);
            *(unsigned long long*)&sX[px*136 + cg] = pk;
        }
        __syncthreads();
        #pragma unroll
        for(int ks=0; ks<4; ks++){
            int k0 = ks << 5;
            short8 bfr = *(const short8*)&sX[(wp + m16)*136 + k0 + (quad<<3)];
            #pragma unroll
            for(int qt=0;qt<2;qt++){
                short8 afr = *(const short8*)&sW[((qt<<4) + m16)*136 + k0 + (quad<<3)];
                acc[qt] = __builtin_amdgcn_mfma_f32_16x16x32_bf16(afr, bfr, acc[qt], 0,0,0);
            }
        }
        __syncthreads();
    }
    if(!swapD){
        #pragma unroll
        for(int qt=0;qt<2;qt++){
            int px = pix0 + wp + m16;
            #pragma unroll
            for(int r=0;r<4;r++){
                int q = (qt<<4) + (quad<<2) + r;
                if(q < 27){
                    float v = acc[qt][r] + ((q<18) ? pb[q] : mb[q-18]);
                    if(q>=18) v = 1.f/(1.f+expf(-v));
                    OM[((b*27+q)<<12) + px] = v;
                }
            }
        }
    } else {
        #pragma unroll
        for(int qt=0;qt<2;qt++){
            int q = (qt<<4) + m16;
            if(q < 27){
                float bias = (q<18) ? pb[q] : mb[q-18];
                #pragma unroll
                for(int r=0;r<4;r++){
                    int px = pix0 + wp + (quad<<2) + r;
                    float v = acc[qt][r] + bias;
                    if(q>=18) v = 1.f/(1.f+expf(-v));
                    OM[((b*27+q)<<12) + px] = v;
                }
            }
        }
    }
}

// ---------------- K5 v5: deformable sampling + bf16 MFMA combine.
// v4 post-mortem: spill gone (WRITE 17 MB), dur 63.5 us, VALUBusy 43% / Occ 22%.
// v5: (a) bilinear meta computed ONCE per (px,corner) into LDS sM (was 32x
// redundant per-thread VALU); (b) sW dropped — A-fragments read direct from
// L2-resident Wbf (288 KB); LDS 52.2K -> 19.5K, 1 barrier/tap (was 2).
// Meta pipelined 2 taps ahead, gather 1 ahead (dbuf sX), MFMA on current.
#define K5_META(t, buf) do{ if(tid < 128){ \
    int px_ = tid >> 2, k_ = tid & 3; \
    int pix_ = pix0 + px_; \
    int yq_ = pix_ >> 6, xq_ = pix_ & 63; \
    int kyy_ = (t)/3, kxx_ = (t)-kyy_*3; \
    float oxv_ = omb[((t)<<12)+pix_]; \
    float oyv_ = omb[(((t)+9)<<12)+pix_]; \
    float mv_  = omb[(((t)+18)<<12)+pix_]; \
    float pxf_ = (float)(yq_ + kyy_) + oxv_; \
    float pyf_ = (float)(xq_ + kxx_) + oyv_; \
    float fx_ = floorf(pxf_), fy_ = floorf(pyf_); \
    float qx0_ = fminf(fmaxf(fx_,0.f),65.f),  qx1_ = fminf(fmaxf(fx_+1.f,0.f),65.f); \
    float qy0_ = fminf(fmaxf(fy_,0.f),65.f),  qy1_ = fminf(fmaxf(fy_+1.f,0.f),65.f); \
    float pxc_ = fminf(fmaxf(pxf_,0.f),65.f), pyc_ = fminf(fmaxf(pyf_,0.f),65.f); \
    float dx0_ = 1.f+(qx0_-pxc_), dx1_ = 1.f-(qx1_-pxc_); \
    float dy0_ = 1.f+(qy0_-pyc_), dy1_ = 1.f-(qy1_-pyc_); \
    int ax0_=(int)qx0_, ax1_=(int)qx1_, ay0_=(int)qy0_, ay1_=(int)qy1_; \
    bool vx0_ = (ax0_>=1)&&(ax0_<=64), vx1_ = (ax1_>=1)&&(ax1_<=64); \
    bool vy0_ = (ay0_>=1)&&(ay0_<=64), vy1_ = (ay1_>=1)&&(ay1_<=64); \
    int  axs_ = (k_&1) ? ax1_ : ax0_; \
    int  ays_ = (k_==1||k_==2) ? ay1_ : ay0_; \
    bool vxs_ = (k_&1) ? vx1_ : vx0_; \
    bool vys_ = (k_==1||k_==2) ? vy1_ : vy0_; \
    float dxs_ = (k_&1) ? dx1_ : dx0_; \
    float dys_ = (k_==1||k_==2) ? dy1_ : dy0_; \
    bool v_ = vxs_ && vys_; \
    int base_ = v_ ? (((axs_-1)<<6)+(ays_-1)) : 0; \
    float g_ = v_ ? dxs_*dys_*mv_ : 0.f; \
    sM[buf][tid] = make_uint2((unsigned)base_, __float_as_uint(g_)); \
} }while(0)

#define K5_GATHER(buf_m, bufp) do{ \
    _Pragma("unroll") \
    for(int j_=0;j_<4;j_++){ \
        int px_ = pxb + (j_<<3); \
        uint2 e0_ = sM[buf_m][(px_<<2)+0]; \
        uint2 e1_ = sM[buf_m][(px_<<2)+1]; \
        uint2 e2_ = sM[buf_m][(px_<<2)+2]; \
        uint2 e3_ = sM[buf_m][(px_<<2)+3]; \
        float g0_ = __uint_as_float(e0_.y), g1_ = __uint_as_float(e1_.y); \
        float g2_ = __uint_as_float(e2_.y), g3_ = __uint_as_float(e3_.y); \
        float4 r0_ = *(const float4*)&cb[((size_t)e0_.x<<7) + cg4]; \
        float4 r1_ = *(const float4*)&cb[((size_t)e1_.x<<7) + cg4]; \
        float4 r2_ = *(const float4*)&cb[((size_t)e2_.x<<7) + cg4]; \
        float4 r3_ = *(const float4*)&cb[((size_t)e3_.x<<7) + cg4]; \
        float vx_ = g0_*r0_.x + g1_*r1_.x + g2_*r2_.x + g3_*r3_.x; \
        float vy_ = g0_*r0_.y + g1_*r1_.y + g2_*r2_.y + g3_*r3_.y; \
        float vz_ = g0_*r0_.z + g1_*r1_.z + g2_*r2_.z + g3_*r3_.z; \
        float vw_ = g0_*r0_.w + g1_*r1_.w + g2_*r2_.w + g3_*r3_.w; \
        unsigned long long pk_ = (unsigned long long)f2bf(vx_) \
            | ((unsigned long long)f2bf(vy_)<<16) \
            | ((unsigned long long)f2bf(vz_)<<32) \
            | ((unsigned long long)f2bf(vw_)<<48); \
        *(unsigned long long*)&(bufp)[px_*136 + cg4] = pk_; \
    } }while(0)

#define K5_DOMFMA(t, srcp) do{ \
    const unsigned short* wn_ = Wbf + ((t)<<14); \
    _Pragma("unroll") \
    for(int ks_=0; ks_<4; ks_++){ \
        int k0_ = ks_ << 5; \
        short8 bfr0 = *(const short8*)&(srcp)[(m16)*136 + k0_ + (quad<<3)]; \
        short8 bfr1 = *(const short8*)&(srcp)[(16 + m16)*136 + k0_ + (quad<<3)]; \
        _Pragma("unroll") \
        for(int ot_=0;ot_<2;ot_++){ \
            short8 afr = *(const short8*)&wn_[(wo + (ot_<<4) + m16)*128 + k0_ + (quad<<3)]; \
            acc[ot_][0] = __builtin_amdgcn_mfma_f32_16x16x32_bf16(afr, bfr0, acc[ot_][0], 0,0,0); \
            acc[ot_][1] = __builtin_amdgcn_mfma_f32_16x16x32_bf16(afr, bfr1, acc[ot_][1], 0,0,0); \
        } } }while(0)

__global__ __launch_bounds__(256, 4) void k_deform(fp Ccl, fp OM, const unsigned short* Wbf,
                                                   float* D, float* stats){
    __shared__ __align__(16) unsigned short sX[2][32*136];   // 17,408 B dbuf [px][c]
    __shared__ __align__(8)  uint2 sM[2][128];               // 2,048 B meta dbuf (base,weight)
    int b = blockIdx.x & 7;
    int pix0 = (blockIdx.x >> 3) << 5;   // 128 tiles x 32 px
    int tid = threadIdx.x;
    int lane = tid & 63, wave = tid >> 6;
    int m16 = lane & 15, quad = lane >> 4;
    int wo = wave << 5;                  // each wave owns 32 output channels
    int cg4 = (tid & 31) << 2;           // channel group (4 ch)
    int pxb = tid >> 5;                  // base px 0..7 (handles px pxb, +8, +16, +24)
    const float* omb = OM + b*27*4096;
    const float* cb  = Ccl + ((size_t)(b)<<12)*128;

    // ---- probe
    short8 ap = {0,0,0,0,0,0,0,0}, bpr = {0,0,0,0,0,0,0,0};
    if(quad == 0){
        ap[0]  = (short)f2bf((float)m16);
        bpr[0] = (short)f2bf((float)(m16+100));
    }
    f32x4 dp = {0.f,0.f,0.f,0.f};
    dp = __builtin_amdgcn_mfma_f32_16x16x32_bf16(ap, bpr, dp, 0,0,0);
    bool p1 = true;
    #pragma unroll
    for(int r=0;r<4;r++){
        float expP1 = (float)(quad*4+r) * (float)(m16+100);
        p1 = p1 && (fabsf(dp[r]-expP1) < 0.5f);
    }
    bool swapD = (__ballot(p1) != 0xFFFFFFFFFFFFFFFFull);

    f32x4 acc[2][2];                     // [ot][pt]
    #pragma unroll
    for(int i=0;i<2;i++){
        #pragma unroll
        for(int j=0;j<2;j++) acc[i][j] = (f32x4){0.f,0.f,0.f,0.f};
    }

    // ---- prologue: meta(0)->sM[0], meta(1)->sM[1]; gather(0)->sX[0]
    K5_META(0, 0);
    K5_META(1, 1);
    __syncthreads();                      // sM[0], sM[1] ready
    K5_GATHER(0, (&sX[0][0]));
    __syncthreads();                      // sX[0] ready

    for(int n=0;n<9;n++){
        if(n<8) K5_GATHER(((n+1)&1), (&sX[(n+1)&1][0]));  // overlaps MFMA(n)
        if(n<7) K5_META(n+2, (n&1));                      // meta 2 taps ahead
        K5_DOMFMA(n, (&sX[n&1][0]));                      // afr direct from L2 Wbf
        __syncthreads();                  // sX[(n+1)&1], sM[n&1] ready for next iter
    }

    // epilogue: D writes + per-channel sum/sumsq reduction (stats LDS overlaid on dead sX)
    float* sdq = (float*)&sX[0][0];       // [0..127]=sum, [128..255]=sumsq
    sdq[tid] = 0.f;                       // 256 threads init 256 floats
    __syncthreads();
    if(!swapD){
        #pragma unroll
        for(int ot=0;ot<2;ot++){
            #pragma unroll
            for(int pt=0;pt<2;pt++){
                int px = pix0 + (pt<<4) + m16;
                #pragma unroll
                for(int r=0;r<4;r++){
                    int o = wo + (ot<<4) + (quad<<2) + r;
                    D[((b*128+o)<<12) + px] = acc[ot][pt][r];
                }
            }
        }
        #pragma unroll
        for(int ot=0;ot<2;ot++){
            #pragma unroll
            for(int r=0;r<4;r++){
                float s  = acc[ot][0][r] + acc[ot][1][r];
                float s2 = acc[ot][0][r]*acc[ot][0][r] + acc[ot][1][r]*acc[ot][1][r];
                #pragma unroll
                for(int msk=1; msk<16; msk<<=1){
                    s  += __shfl_xor(s, msk, 64);
                    s2 += __shfl_xor(s2, msk, 64);
                }
                if(m16 == 0){
                    int o = wo + (ot<<4) + (quad<<2) + r;
                    atomicAdd(&sdq[o], s);
                    atomicAdd(&sdq[128+o], s2);
                }
            }
        }
    } else {
        #pragma unroll
        for(int ot=0;ot<2;ot++){
            #pragma unroll
            for(int pt=0;pt<2;pt++){
                int o = wo + (ot<<4) + m16;
                #pragma unroll
                for(int r=0;r<4;r++){
                    int px = pix0 + (pt<<4) + (quad<<2) + r;
                    D[((b*128+o)<<12) + px] = acc[ot][pt][r];
                }
            }
        }
        #pragma unroll
        for(int ot=0;ot<2;ot++){
            float s = 0.f, s2 = 0.f;
            #pragma unroll
            for(int pt=0;pt<2;pt++){
                #pragma unroll
                for(int r=0;r<4;r++){
                    float v = acc[ot][pt][r];
                    s += v; s2 += v*v;
                }
            }
            #pragma unroll
            for(int msk=16; msk<64; msk<<=1){
                s  += __shfl_xor(s, msk, 64);
                s2 += __shfl_xor(s2, msk, 64);
            }
            if(quad == 0){
                int o = wo + (ot<<4) + m16;
                atomicAdd(&sdq[o], s);
                atomicAdd(&sdq[128+o], s2);
            }
        }
    }
    __syncthreads();
    if(tid < 128){
        atomicAdd(&stats[tid],     sdq[tid]);
        atomicAdd(&stats[128+tid], sdq[128+tid]);
    }
}

// ---------------- K7: fused BN1+GELU + depthwise128 -> Hs, + atomic stats2 partials
// float4 staging + float4 conv epilogue.
__global__ __launch_bounds__(256) void k_bngelu_dw128(const float* Dsrc, float* stats,
                                                      fp g1, fp b1, fp w, fp bias, float* Hs){
    __shared__ float sG[66*68 + 4];
    __shared__ float sd[256], sq[256];
    int bid = blockIdx.x;
    int c = bid & 127, b = bid >> 7;
    int tid = threadIdx.x;
    float mean1 = stats[c] * (1.f/32768.f);
    float var1  = stats[128+c] * (1.f/32768.f) - mean1*mean1;
    float rstd1 = rsqrtf(var1 + 1e-5f);
    float sc = rstd1 * g1[c];
    float sb = b1[c] - mean1*sc;
    // zero halo ring
    for(int j = tid; j < 264; j += 256){
        int idx;
        if(j < 66)       idx = j;
        else if(j < 132) idx = 65*68 + (j-66);
        else if(j < 196) idx = (j-132+1)*68;
        else if(j < 260) idx = (j-196+1)*68 + 65;
        else             idx = 66*68 + (j-260);
        sG[idx] = 0.f;
    }
    const float* dplane = Dsrc + ((size_t)(b*128+c)<<12);
    for(int j = tid; j < 1024; j += 256){           // 64 rows x 16 float4, BN1+GELU
        int yy = j >> 4, x4 = (j & 15) << 2;
        float4 v = *(const float4*)&dplane[(yy<<6) + x4];
        float g0 = v.x*sc+sb, g1v = v.y*sc+sb, g2 = v.z*sc+sb, g3 = v.w*sc+sb;
        float* d = &sG[(yy+1)*68 + x4 + 1];
        d[0] = 0.5f*g0*(1.0f + erff(g0*0.70710678118654752f));
        d[1] = 0.5f*g1v*(1.0f + erff(g1v*0.70710678118654752f));
        d[2] = 0.5f*g2*(1.0f + erff(g2*0.70710678118654752f));
        d[3] = 0.5f*g3*(1.0f + erff(g3*0.70710678118654752f));
    }
    __syncthreads();
    float w0=w[c*9+0], w1=w[c*9+1], w2=w[c*9+2];
    float w3=w[c*9+3], w4=w[c*9+4], w5=w[c*9+5];
    float w6=w[c*9+6], w7=w[c*9+7], w8=w[c*9+8];
    float bv = bias[c];
    float* dst = Hs + ((size_t)(b*128+c)<<12);
    float s = 0.f, s2 = 0.f;
    for(int j = tid; j < 1024; j += 256){           // 64 rows x 16 float4
        int y = j >> 4, x0 = (j & 15) << 2;
        float a0=bv, a1=bv, a2=bv, a3=bv;
        #pragma unroll
        for(int ky=0; ky<3; ky++){
            const float* rr = &sG[(y+ky)*68 + x0];
            float4 u0 = *(const float4*)&rr[0];
            float2 u1 = *(const float2*)&rr[4];
            float wA = (ky==0)?w0:((ky==1)?w3:w6);
            float wB = (ky==0)?w1:((ky==1)?w4:w7);
            float wC = (ky==0)?w2:((ky==1)?w5:w8);
            a0 += wA*u0.x + wB*u0.y + wC*u0.z;
            a1 += wA*u0.y + wB*u0.z + wC*u0.w;
            a2 += wA*u0.z + wB*u0.w + wC*u1.x;
            a3 += wA*u0.w + wB*u1.x + wC*u1.y;
        }
        *(float4*)&dst[(y<<6)+x0] = make_float4(a0,a1,a2,a3);
        s += a0+a1+a2+a3;
        s2 += a0*a0 + a1*a1 + a2*a2 + a3*a3;
    }
    sd[tid]=s; sq[tid]=s2; __syncthreads();
    for(int off=128; off>0; off>>=1){
        if(tid<off){ sd[tid]+=sd[tid+off]; sq[tid]+=sq[tid+off]; }
        __syncthreads();
    }
    if(tid==0){
        atomicAdd(&stats[256+c], sd[0]);
        atomicAdd(&stats[384+c], sq[0]);
    }
}

// ---------------- BN2 + ReLU -> f32 out (float4; finalizes stats2 sums inline)
__global__ __launch_bounds__(256) void k_bn_relu_out(const float* Hs, const float* stats, fp g, fp bb, float* out){
    int idx = blockIdx.x*256+threadIdx.x;       // 1,048,576 float4
    int c = (idx>>10)&127;
    float mean2 = stats[256+c] * (1.f/32768.f);
    float var2  = stats[384+c] * (1.f/32768.f) - mean2*mean2;
    float rs = rsqrtf(var2 + 1e-5f) * g[c];
    float sb = bb[c] - mean2*rs;
    float4 v = ((const float4*)Hs)[idx];
    float4 o;
    o.x = fmaxf(v.x*rs+sb, 0.f);
    o.y = fmaxf(v.y*rs+sb, 0.f);
    o.z = fmaxf(v.z*rs+sb, 0.f);
    o.w = fmaxf(v.w*rs+sb, 0.f);
    ((float4*)out)[idx] = o;
}

extern "C" void kernel_launch(void* const* d_in, const int* in_sizes, int n_in,
                              void* d_out, int out_size, void* d_ws, size_t ws_size,
                              hipStream_t stream){
    fp x1   = (fp)d_in[0];
    fp x2   = (fp)d_in[1];
    fp dw_w = (fp)d_in[2];  fp dw_b = (fp)d_in[3];
    fp pw_w = (fp)d_in[4];  fp pw_b = (fp)d_in[5];
    fp p_w  = (fp)d_in[6];  fp p_b  = (fp)d_in[7];
    fp m_w  = (fp)d_in[8];  fp m_b  = (fp)d_in[9];
    fp dcn_w= (fp)d_in[10];
    fp bn1g = (fp)d_in[11]; fp bn1b = (fp)d_in[12];
    fp dw2w = (fp)d_in[13]; fp dw2b = (fp)d_in[14];
    fp bn2g = (fp)d_in[15]; fp bn2b = (fp)d_in[16];

    float* ws  = (float*)d_ws;
    float* Bo  = ws;                    // (8,256,4096) = 8,388,608 f ; D reuses after k_pw
    float* Ccl = ws + 8388608;          // (8,4096,128) = 4,194,304 f ; Hs reuses after k_deform
    float* OM  = ws + 12582912;         // (8,27,4096)  =   884,736 f
    unsigned short* Wbf = (unsigned short*)(ws + 13467648);  // 147,456 bf16 (73,728 f)
    unsigned short* Wpm = (unsigned short*)(ws + 13541376);  //  36,864 bf16 (18,432 f)
    float* stats = ws + 13559808;       // 512 f (sum1, sq1, sum2, sq2)
    float* Wpwt  = ws + 13560320;       // 32,768 f (pw_w transposed [c][o])
    float* D   = Bo;                    // Bo dead after k_pw
    float* Hs  = Ccl;                   // Ccl dead after k_deform
    float* out = (float*)d_out;

    hipMemsetAsync(stats, 0, 512*sizeof(float), stream);
    k_prep         <<<848,   256, 0, stream>>>(dcn_w, p_w, m_w, pw_w, Wbf, Wpm, Wpwt);
    k_updw256      <<<2048,  256, 0, stream>>>(x1, x2, dw_w, dw_b, Bo);
    k_pw           <<<1024,  256, 0, stream>>>(Bo, Wpwt, pw_b, Ccl);
    k_offmask      <<<512,   256, 0, stream>>>(Ccl, Wpm, p_b, m_b, OM);
    k_deform       <<<1024,  256, 0, stream>>>(Ccl, OM, Wbf, D, stats);
    k_bngelu_dw128 <<<1024,  256, 0, stream>>>(D, stats, bn1g, bn1b, dw2w, dw2b, Hs);
    k_bn_relu_out  <<<4096,  256, 0, stream>>>(Hs, stats, bn2g, bn2b, out);
}

// Round 6
// 259.209 us; speedup vs baseline: 1.0742x; 1.0742x over previous
//
#include <hip/hip_runtime.h>
#include <math.h>

// Problem constants: B=8, spatial 64x64 (HW=4096), C_mid=256, C=128, N=9 taps.
// All inputs/outputs are float32.
typedef const float* fp;
typedef __attribute__((ext_vector_type(8))) short short8;   // 8 bf16 = 4 VGPRs (MFMA A/B frag)
typedef __attribute__((ext_vector_type(4))) float f32x4;    // MFMA C/D frag

__device__ __forceinline__ unsigned short f2bf(float f){    // RTNE float->bf16
    unsigned u = __float_as_uint(f);
    u += 0x7fff + ((u >> 16) & 1);
    return (unsigned short)(u >> 16);
}

// ---------------- K0: merged prep — Wbf[n][o][c] bf16, Wpm[n][32q][128c] bf16, Wpwt[c][128o] f32
__global__ __launch_bounds__(256) void k_prep(fp dcn_w, fp pw, fp mw, fp pww,
                                              unsigned short* Wbf, unsigned short* Wpm, float* Wpwt){
    int i = blockIdx.x*256 + threadIdx.x;       // 217088 = 848 blocks
    if(i < 147456){
        int c = i & 127, o = (i >> 7) & 127, n = i >> 14;
        Wbf[i] = f2bf(dcn_w[o*1152 + c*9 + n]);
    } else if(i < 184320){
        int j = i - 147456;
        int c = j & 127, q = (j >> 7) & 31, n = j >> 12;
        float v = 0.f;
        if(q < 18)      v = pw[q*1152 + c*9 + n];
        else if(q < 27) v = mw[(q-18)*1152 + c*9 + n];
        Wpm[j] = f2bf(v);
    } else {
        int j = i - 184320;                     // 32768
        int o = j & 127, c = j >> 7;
        Wpwt[c*128 + o] = pww[o*256 + c];
    }
}

// ---------------- K1: fused upsample+concat+depthwise256 -> Bo (8,256,64,64)
// float4 staging (x2 path) + float4 conv epilogue.
__global__ __launch_bounds__(256) void k_updw256(fp x1, fp x2, fp w, fp bias, float* Bo){
    __shared__ float sA[66*68 + 4];
    int bid = blockIdx.x;
    int c = bid & 255, b = bid >> 8;
    int tid = threadIdx.x;
    // zero halo ring (rows 0/65, cols 0/65) + pad
    for(int j = tid; j < 264; j += 256){
        int idx;
        if(j < 66)       idx = j;
        else if(j < 132) idx = 65*68 + (j-66);
        else if(j < 196) idx = (j-132+1)*68;
        else if(j < 260) idx = (j-196+1)*68 + 65;
        else             idx = 66*68 + (j-260);
        sA[idx] = 0.f;
    }
    if(c < 128){
        const float* src = x2 + ((size_t)(b*128+c)<<12);
        for(int j = tid; j < 1024; j += 256){       // 64 rows x 16 float4
            int yy = j >> 4, x4 = (j & 15) << 2;
            float4 v = *(const float4*)&src[(yy<<6) + x4];
            float* d = &sA[(yy+1)*68 + x4 + 1];
            d[0]=v.x; d[1]=v.y; d[2]=v.z; d[3]=v.w;
        }
    } else {
        int cc = c - 128;
        fp src = x1 + ((b*128+cc)<<10);
        const float s = 31.0f/63.0f;
        for(int j = tid; j < 4096; j += 256){
            int yy = j >> 6, xx = j & 63;
            float fy = yy*s, fx = xx*s;
            int iy = (int)fy; if (iy > 30) iy = 30;
            int ix = (int)fx; if (ix > 30) ix = 30;
            float ty = fy - (float)iy, tx = fx - (float)ix;
            float v00 = src[iy*32+ix],     v01 = src[iy*32+ix+1];
            float v10 = src[(iy+1)*32+ix], v11 = src[(iy+1)*32+ix+1];
            sA[(yy+1)*68 + xx + 1] =
                (v00*(1.f-ty)+v10*ty)*(1.f-tx) + (v01*(1.f-ty)+v11*ty)*tx;
        }
    }
    __syncthreads();
    float w0=w[c*9+0], w1=w[c*9+1], w2=w[c*9+2];
    float w3=w[c*9+3], w4=w[c*9+4], w5=w[c*9+5];
    float w6=w[c*9+6], w7=w[c*9+7], w8=w[c*9+8];
    float bv = bias[c];
    float* dst = Bo + ((size_t)(b*256+c)<<12);
    for(int j = tid; j < 1024; j += 256){           // 64 rows x 16 float4
        int y = j >> 4, x0 = (j & 15) << 2;
        float a0=bv, a1=bv, a2=bv, a3=bv;
        #pragma unroll
        for(int ky=0; ky<3; ky++){
            const float* rr = &sA[(y+ky)*68 + x0];
            float4 u0 = *(const float4*)&rr[0];
            float2 u1 = *(const float2*)&rr[4];
            float wA = (ky==0)?w0:((ky==1)?w3:w6);
            float wB = (ky==0)?w1:((ky==1)?w4:w7);
            float wC = (ky==0)?w2:((ky==1)?w5:w8);
            a0 += wA*u0.x + wB*u0.y + wC*u0.z;
            a1 += wA*u0.y + wB*u0.z + wC*u0.w;
            a2 += wA*u0.z + wB*u0.w + wC*u1.x;
            a3 += wA*u0.w + wB*u1.x + wC*u1.y;
        }
        *(float4*)&dst[(y<<6)+x0] = make_float4(a0,a1,a2,a3);
    }
}

// ---------------- K3: pointwise 256->128 + bias -> Ccl (channel-last), transposed f32 weights
__global__ __launch_bounds__(256) void k_pw(const float* Bi, fp Wt, fp bias, float* Ccl){
    __shared__ float sIn[256*32];
    int bid = blockIdx.x;                       // 1024
    int b = bid >> 7;
    int pix0 = (bid & 127) << 5;
    int tid = threadIdx.x;
    for(int j = tid; j < 256*32; j += 256){
        int c = j >> 5, p = j & 31;
        sIn[j] = Bi[((b*256 + c)<<12) + pix0 + p];
    }
    __syncthreads();
    int og = tid >> 3, pg = tid & 7;
    int o0 = og*4, p0 = pg*4;
    float acc[4][4];
    #pragma unroll
    for(int i=0;i<4;i++){ float bv=bias[o0+i];
        #pragma unroll
        for(int j=0;j<4;j++) acc[i][j]=bv; }
    for(int c=0;c<256;c++){
        float4 xv = *(const float4*)&sIn[(c<<5)+p0];
        float4 w4 = *(const float4*)&Wt[(c<<7)+o0];
        acc[0][0]+=w4.x*xv.x; acc[0][1]+=w4.x*xv.y; acc[0][2]+=w4.x*xv.z; acc[0][3]+=w4.x*xv.w;
        acc[1][0]+=w4.y*xv.x; acc[1][1]+=w4.y*xv.y; acc[1][2]+=w4.y*xv.z; acc[1][3]+=w4.y*xv.w;
        acc[2][0]+=w4.z*xv.x; acc[2][1]+=w4.z*xv.y; acc[2][2]+=w4.z*xv.z; acc[2][3]+=w4.z*xv.w;
        acc[3][0]+=w4.w*xv.x; acc[3][1]+=w4.w*xv.y; acc[3][2]+=w4.w*xv.z; acc[3][3]+=w4.w*xv.w;
    }
    #pragma unroll
    for(int j=0;j<4;j++){
        int px = pix0 + p0 + j;
        *(float4*)&Ccl[((size_t)(b<<12) + px)*128 + o0] =
            make_float4(acc[0][j],acc[1][j],acc[2][j],acc[3][j]);
    }
}

// ---------------- K4: offset(18)+mask(9, sigmoid) 3x3 conv via bf16 MFMA -> OM (8,27,4096)
__global__ __launch_bounds__(256) void k_offmask(fp Ccl, const unsigned short* Wpm,
                                                 fp pb, fp mb, float* OM){
    __shared__ __align__(16) unsigned short sW[32*136];   // [q][c] bf16
    __shared__ __align__(16) unsigned short sX[64*136];   // [px][c] bf16
    int b = blockIdx.x & 7;
    int y = blockIdx.x >> 3;          // output row
    int pix0 = y << 6;
    int tid = threadIdx.x;
    int lane = tid & 63, wave = tid >> 6;
    int m16 = lane & 15, quad = lane >> 4;
    int wp = wave << 4;               // px-subtile
    const float* cb = Ccl + (size_t)(b<<12)*128;

    // ---- probe: D[m][n]=m*(n+100)
    short8 ap = {0,0,0,0,0,0,0,0}, bpr = {0,0,0,0,0,0,0,0};
    if(quad == 0){
        ap[0]  = (short)f2bf((float)m16);
        bpr[0] = (short)f2bf((float)(m16+100));
    }
    f32x4 dp = {0.f,0.f,0.f,0.f};
    dp = __builtin_amdgcn_mfma_f32_16x16x32_bf16(ap, bpr, dp, 0,0,0);
    bool p1 = true;
    #pragma unroll
    for(int r=0;r<4;r++){
        float expP1 = (float)(quad*4+r) * (float)(m16+100);
        p1 = p1 && (fabsf(dp[r]-expP1) < 0.5f);
    }
    bool swapD = (__ballot(p1) != 0xFFFFFFFFFFFFFFFFull);

    f32x4 acc[2];
    acc[0] = (f32x4){0.f,0.f,0.f,0.f};
    acc[1] = (f32x4){0.f,0.f,0.f,0.f};

    for(int n=0;n<9;n++){
        int ky = n/3, kx = n - ky*3;
        int yy = y + ky - 1;
        bool rowok = (yy>=0 && yy<64);
        const int4* wsrc = (const int4*)(Wpm + (n<<12));
        for(int j=tid; j<512; j+=256){
            int q = j >> 4, cg = j & 15;
            *(int4*)&sW[q*136 + (cg<<3)] = wsrc[j];
        }
        #pragma unroll
        for(int it=0; it<8; it++){
            int e = tid + (it<<8);
            int cg = (e & 31) << 2, px = e >> 5;
            int xx = px + kx - 1;
            float4 v = make_float4(0.f,0.f,0.f,0.f);
            if(rowok && xx>=0 && xx<64)
                v = *(const float4*)&cb[(size_t)((yy<<6)+xx)*128 + cg];
            unsigned long long pk = (unsigned long long)f2bf(v.x)
                | ((unsigned long long)f2bf(v.y)<<16)
                | ((unsigned long long)f2bf(v.z)<<32)
                | ((unsigned long long)f2bf(v.w)<<48);
            *(unsigned long long*)&sX[px*136 + cg] = pk;
        }
        __syncthreads();
        #pragma unroll
        for(int ks=0; ks<4; ks++){
            int k0 = ks << 5;
            short8 bfr = *(const short8*)&sX[(wp + m16)*136 + k0 + (quad<<3)];
            #pragma unroll
            for(int qt=0;qt<2;qt++){
                short8 afr = *(const short8*)&sW[((qt<<4) + m16)*136 + k0 + (quad<<3)];
                acc[qt] = __builtin_amdgcn_mfma_f32_16x16x32_bf16(afr, bfr, acc[qt], 0,0,0);
            }
        }
        __syncthreads();
    }
    if(!swapD){
        #pragma unroll
        for(int qt=0;qt<2;qt++){
            int px = pix0 + wp + m16;
            #pragma unroll
            for(int r=0;r<4;r++){
                int q = (qt<<4) + (quad<<2) + r;
                if(q < 27){
                    float v = acc[qt][r] + ((q<18) ? pb[q] : mb[q-18]);
                    if(q>=18) v = 1.f/(1.f+expf(-v));
                    OM[((b*27+q)<<12) + px] = v;
                }
            }
        }
    } else {
        #pragma unroll
        for(int qt=0;qt<2;qt++){
            int q = (qt<<4) + m16;
            if(q < 27){
                float bias = (q<18) ? pb[q] : mb[q-18];
                #pragma unroll
                for(int r=0;r<4;r++){
                    int px = pix0 + wp + (quad<<2) + r;
                    float v = acc[qt][r] + bias;
                    if(q>=18) v = 1.f/(1.f+expf(-v));
                    OM[((b*27+q)<<12) + px] = v;
                }
            }
        }
    }
}

// ---------------- K5 v6: deformable sampling + bf16 MFMA combine.
// v5 post-mortem: meta-in-LDS good (VALU 43->18), weights-from-L2 bad (MFMA
// stalled on global afr loads; 63.5 -> 80 us). v6 = v4 skeleton (sW staged in
// LDS, 2 barriers/tap, bounds(256,3)) + single-buffered sM meta (1 KB) computed
// one slot ahead in the same inter-barrier phase as the sW stage.
// LDS = 34,816 + 17,408 + 1,024 = 53,248 B -> 3 blocks/CU exactly.
#define K5_META(t) do{ if(tid < 128){ \
    int px_ = tid >> 2, k_ = tid & 3; \
    int pix_ = pix0 + px_; \
    int yq_ = pix_ >> 6, xq_ = pix_ & 63; \
    int kyy_ = (t)/3, kxx_ = (t)-kyy_*3; \
    float oxv_ = omb[((t)<<12)+pix_]; \
    float oyv_ = omb[(((t)+9)<<12)+pix_]; \
    float mv_  = omb[(((t)+18)<<12)+pix_]; \
    float pxf_ = (float)(yq_ + kyy_) + oxv_; \
    float pyf_ = (float)(xq_ + kxx_) + oyv_; \
    float fx_ = floorf(pxf_), fy_ = floorf(pyf_); \
    float qx0_ = fminf(fmaxf(fx_,0.f),65.f),  qx1_ = fminf(fmaxf(fx_+1.f,0.f),65.f); \
    float qy0_ = fminf(fmaxf(fy_,0.f),65.f),  qy1_ = fminf(fmaxf(fy_+1.f,0.f),65.f); \
    float pxc_ = fminf(fmaxf(pxf_,0.f),65.f), pyc_ = fminf(fmaxf(pyf_,0.f),65.f); \
    float dx0_ = 1.f+(qx0_-pxc_), dx1_ = 1.f-(qx1_-pxc_); \
    float dy0_ = 1.f+(qy0_-pyc_), dy1_ = 1.f-(qy1_-pyc_); \
    int ax0_=(int)qx0_, ax1_=(int)qx1_, ay0_=(int)qy0_, ay1_=(int)qy1_; \
    bool vx0_ = (ax0_>=1)&&(ax0_<=64), vx1_ = (ax1_>=1)&&(ax1_<=64); \
    bool vy0_ = (ay0_>=1)&&(ay0_<=64), vy1_ = (ay1_>=1)&&(ay1_<=64); \
    int  axs_ = (k_&1) ? ax1_ : ax0_; \
    int  ays_ = (k_==1||k_==2) ? ay1_ : ay0_; \
    bool vxs_ = (k_&1) ? vx1_ : vx0_; \
    bool vys_ = (k_==1||k_==2) ? vy1_ : vy0_; \
    float dxs_ = (k_&1) ? dx1_ : dx0_; \
    float dys_ = (k_==1||k_==2) ? dy1_ : dy0_; \
    bool v_ = vxs_ && vys_; \
    int base_ = v_ ? (((axs_-1)<<6)+(ays_-1)) : 0; \
    float g_ = v_ ? dxs_*dys_*mv_ : 0.f; \
    sM[tid] = make_uint2((unsigned)base_, __float_as_uint(g_)); \
} }while(0)

#define K5_GATHER(bufp) do{ \
    _Pragma("unroll") \
    for(int j_=0;j_<4;j_++){ \
        int px_ = pxb + (j_<<3); \
        uint2 e0_ = sM[(px_<<2)+0]; \
        uint2 e1_ = sM[(px_<<2)+1]; \
        uint2 e2_ = sM[(px_<<2)+2]; \
        uint2 e3_ = sM[(px_<<2)+3]; \
        float g0_ = __uint_as_float(e0_.y), g1_ = __uint_as_float(e1_.y); \
        float g2_ = __uint_as_float(e2_.y), g3_ = __uint_as_float(e3_.y); \
        float4 r0_ = *(const float4*)&cb[((size_t)e0_.x<<7) + cg4]; \
        float4 r1_ = *(const float4*)&cb[((size_t)e1_.x<<7) + cg4]; \
        float4 r2_ = *(const float4*)&cb[((size_t)e2_.x<<7) + cg4]; \
        float4 r3_ = *(const float4*)&cb[((size_t)e3_.x<<7) + cg4]; \
        float vx_ = g0_*r0_.x + g1_*r1_.x + g2_*r2_.x + g3_*r3_.x; \
        float vy_ = g0_*r0_.y + g1_*r1_.y + g2_*r2_.y + g3_*r3_.y; \
        float vz_ = g0_*r0_.z + g1_*r1_.z + g2_*r2_.z + g3_*r3_.z; \
        float vw_ = g0_*r0_.w + g1_*r1_.w + g2_*r2_.w + g3_*r3_.w; \
        unsigned long long pk_ = (unsigned long long)f2bf(vx_) \
            | ((unsigned long long)f2bf(vy_)<<16) \
            | ((unsigned long long)f2bf(vz_)<<32) \
            | ((unsigned long long)f2bf(vw_)<<48); \
        *(unsigned long long*)&(bufp)[px_*136 + cg4] = pk_; \
    } }while(0)

#define K5_STAGE_W(t) do{ \
    const int4* wsrc_ = (const int4*)(Wbf + ((t)<<14)); \
    _Pragma("unroll") \
    for(int k_=0;k_<8;k_++){ int j_ = tid + (k_<<8); \
        *(int4*)&sW[(j_>>4)*136 + ((j_&15)<<3)] = wsrc_[j_]; } }while(0)

#define K5_DOMFMA(srcp) do{ \
    _Pragma("unroll") \
    for(int ks_=0; ks_<4; ks_++){ \
        int k0_ = ks_ << 5; \
        short8 bfr0 = *(const short8*)&(srcp)[(m16)*136 + k0_ + (quad<<3)]; \
        short8 bfr1 = *(const short8*)&(srcp)[(16 + m16)*136 + k0_ + (quad<<3)]; \
        _Pragma("unroll") \
        for(int ot_=0;ot_<2;ot_++){ \
            short8 afr = *(const short8*)&sW[(wo + (ot_<<4) + m16)*136 + k0_ + (quad<<3)]; \
            acc[ot_][0] = __builtin_amdgcn_mfma_f32_16x16x32_bf16(afr, bfr0, acc[ot_][0], 0,0,0); \
            acc[ot_][1] = __builtin_amdgcn_mfma_f32_16x16x32_bf16(afr, bfr1, acc[ot_][1], 0,0,0); \
        } } }while(0)

__global__ __launch_bounds__(256, 3) void k_deform(fp Ccl, fp OM, const unsigned short* Wbf,
                                                   float* D, float* stats){
    __shared__ __align__(16) unsigned short sW[128*136];     // 34,816 B [o][c]
    __shared__ __align__(16) unsigned short sX[2][32*136];   // 17,408 B dbuf [px][c]
    __shared__ __align__(8)  uint2 sM[128];                  //  1,024 B meta (base,weight)
    int b = blockIdx.x & 7;
    int pix0 = (blockIdx.x >> 3) << 5;   // 128 tiles x 32 px
    int tid = threadIdx.x;
    int lane = tid & 63, wave = tid >> 6;
    int m16 = lane & 15, quad = lane >> 4;
    int wo = wave << 5;                  // each wave owns 32 output channels
    int cg4 = (tid & 31) << 2;           // channel group (4 ch)
    int pxb = tid >> 5;                  // base px 0..7 (handles px pxb, +8, +16, +24)
    const float* omb = OM + b*27*4096;
    const float* cb  = Ccl + ((size_t)(b)<<12)*128;

    // ---- probe
    short8 ap = {0,0,0,0,0,0,0,0}, bpr = {0,0,0,0,0,0,0,0};
    if(quad == 0){
        ap[0]  = (short)f2bf((float)m16);
        bpr[0] = (short)f2bf((float)(m16+100));
    }
    f32x4 dp = {0.f,0.f,0.f,0.f};
    dp = __builtin_amdgcn_mfma_f32_16x16x32_bf16(ap, bpr, dp, 0,0,0);
    bool p1 = true;
    #pragma unroll
    for(int r=0;r<4;r++){
        float expP1 = (float)(quad*4+r) * (float)(m16+100);
        p1 = p1 && (fabsf(dp[r]-expP1) < 0.5f);
    }
    bool swapD = (__ballot(p1) != 0xFFFFFFFFFFFFFFFFull);

    f32x4 acc[2][2];                     // [ot][pt]
    #pragma unroll
    for(int i=0;i<2;i++){
        #pragma unroll
        for(int j=0;j<2;j++) acc[i][j] = (f32x4){0.f,0.f,0.f,0.f};
    }

    // ---- prologue
    K5_META(0);
    __syncthreads();                      // sM = meta(0)
    K5_GATHER((&sX[0][0]));               // gather(0) using meta(0)
    K5_STAGE_W(0);
    __syncthreads();                      // sX[0], sW(0) ready; sM reads done
    K5_META(1);
    __syncthreads();                      // sM = meta(1)

    for(int n=0;n<9;n++){
        if(n<8) K5_GATHER((&sX[(n+1)&1][0]));  // uses sM = meta(n+1); overlaps MFMA(n)
        K5_DOMFMA((&sX[n&1][0]));              // operands from LDS (sW, sX)
        __syncthreads();                       // sW/sM reads + sX writes done
        if(n<8){
            K5_STAGE_W(n+1);                   // sW <- W(n+1), transient regs
            if(n<7) K5_META(n+2);              // sM <- meta(n+2)
            __syncthreads();                   // sW, sM ready for next iter
        }
    }

    // epilogue: D writes + per-channel sum/sumsq reduction (stats LDS overlaid on dead sX)
    float* sdq = (float*)&sX[0][0];       // [0..127]=sum, [128..255]=sumsq
    sdq[tid] = 0.f;                       // 256 threads init 256 floats
    __syncthreads();
    if(!swapD){
        #pragma unroll
        for(int ot=0;ot<2;ot++){
            #pragma unroll
            for(int pt=0;pt<2;pt++){
                int px = pix0 + (pt<<4) + m16;
                #pragma unroll
                for(int r=0;r<4;r++){
                    int o = wo + (ot<<4) + (quad<<2) + r;
                    D[((b*128+o)<<12) + px] = acc[ot][pt][r];
                }
            }
        }
        #pragma unroll
        for(int ot=0;ot<2;ot++){
            #pragma unroll
            for(int r=0;r<4;r++){
                float s  = acc[ot][0][r] + acc[ot][1][r];
                float s2 = acc[ot][0][r]*acc[ot][0][r] + acc[ot][1][r]*acc[ot][1][r];
                #pragma unroll
                for(int msk=1; msk<16; msk<<=1){
                    s  += __shfl_xor(s, msk, 64);
                    s2 += __shfl_xor(s2, msk, 64);
                }
                if(m16 == 0){
                    int o = wo + (ot<<4) + (quad<<2) + r;
                    atomicAdd(&sdq[o], s);
                    atomicAdd(&sdq[128+o], s2);
                }
            }
        }
    } else {
        #pragma unroll
        for(int ot=0;ot<2;ot++){
            #pragma unroll
            for(int pt=0;pt<2;pt++){
                int o = wo + (ot<<4) + m16;
                #pragma unroll
                for(int r=0;r<4;r++){
                    int px = pix0 + (pt<<4) + (quad<<2) + r;
                    D[((b*128+o)<<12) + px] = acc[ot][pt][r];
                }
            }
        }
        #pragma unroll
        for(int ot=0;ot<2;ot++){
            float s = 0.f, s2 = 0.f;
            #pragma unroll
            for(int pt=0;pt<2;pt++){
                #pragma unroll
                for(int r=0;r<4;r++){
                    float v = acc[ot][pt][r];
                    s += v; s2 += v*v;
                }
            }
            #pragma unroll
            for(int msk=16; msk<64; msk<<=1){
                s  += __shfl_xor(s, msk, 64);
                s2 += __shfl_xor(s2, msk, 64);
            }
            if(quad == 0){
                int o = wo + (ot<<4) + m16;
                atomicAdd(&sdq[o], s);
                atomicAdd(&sdq[128+o], s2);
            }
        }
    }
    __syncthreads();
    if(tid < 128){
        atomicAdd(&stats[tid],     sdq[tid]);
        atomicAdd(&stats[128+tid], sdq[128+tid]);
    }
}

// ---------------- K7: fused BN1+GELU + depthwise128 -> Hs, + atomic stats2 partials
// float4 staging + float4 conv epilogue.
__global__ __launch_bounds__(256) void k_bngelu_dw128(const float* Dsrc, float* stats,
                                                      fp g1, fp b1, fp w, fp bias, float* Hs){
    __shared__ float sG[66*68 + 4];
    __shared__ float sd[256], sq[256];
    int bid = blockIdx.x;
    int c = bid & 127, b = bid >> 7;
    int tid = threadIdx.x;
    float mean1 = stats[c] * (1.f/32768.f);
    float var1  = stats[128+c] * (1.f/32768.f) - mean1*mean1;
    float rstd1 = rsqrtf(var1 + 1e-5f);
    float sc = rstd1 * g1[c];
    float sb = b1[c] - mean1*sc;
    // zero halo ring
    for(int j = tid; j < 264; j += 256){
        int idx;
        if(j < 66)       idx = j;
        else if(j < 132) idx = 65*68 + (j-66);
        else if(j < 196) idx = (j-132+1)*68;
        else if(j < 260) idx = (j-196+1)*68 + 65;
        else             idx = 66*68 + (j-260);
        sG[idx] = 0.f;
    }
    const float* dplane = Dsrc + ((size_t)(b*128+c)<<12);
    for(int j = tid; j < 1024; j += 256){           // 64 rows x 16 float4, BN1+GELU
        int yy = j >> 4, x4 = (j & 15) << 2;
        float4 v = *(const float4*)&dplane[(yy<<6) + x4];
        float g0 = v.x*sc+sb, g1v = v.y*sc+sb, g2 = v.z*sc+sb, g3 = v.w*sc+sb;
        float* d = &sG[(yy+1)*68 + x4 + 1];
        d[0] = 0.5f*g0*(1.0f + erff(g0*0.70710678118654752f));
        d[1] = 0.5f*g1v*(1.0f + erff(g1v*0.70710678118654752f));
        d[2] = 0.5f*g2*(1.0f + erff(g2*0.70710678118654752f));
        d[3] = 0.5f*g3*(1.0f + erff(g3*0.70710678118654752f));
    }
    __syncthreads();
    float w0=w[c*9+0], w1=w[c*9+1], w2=w[c*9+2];
    float w3=w[c*9+3], w4=w[c*9+4], w5=w[c*9+5];
    float w6=w[c*9+6], w7=w[c*9+7], w8=w[c*9+8];
    float bv = bias[c];
    float* dst = Hs + ((size_t)(b*128+c)<<12);
    float s = 0.f, s2 = 0.f;
    for(int j = tid; j < 1024; j += 256){           // 64 rows x 16 float4
        int y = j >> 4, x0 = (j & 15) << 2;
        float a0=bv, a1=bv, a2=bv, a3=bv;
        #pragma unroll
        for(int ky=0; ky<3; ky++){
            const float* rr = &sG[(y+ky)*68 + x0];
            float4 u0 = *(const float4*)&rr[0];
            float2 u1 = *(const float2*)&rr[4];
            float wA = (ky==0)?w0:((ky==1)?w3:w6);
            float wB = (ky==0)?w1:((ky==1)?w4:w7);
            float wC = (ky==0)?w2:((ky==1)?w5:w8);
            a0 += wA*u0.x + wB*u0.y + wC*u0.z;
            a1 += wA*u0.y + wB*u0.z + wC*u0.w;
            a2 += wA*u0.z + wB*u0.w + wC*u1.x;
            a3 += wA*u0.w + wB*u1.x + wC*u1.y;
        }
        *(float4*)&dst[(y<<6)+x0] = make_float4(a0,a1,a2,a3);
        s += a0+a1+a2+a3;
        s2 += a0*a0 + a1*a1 + a2*a2 + a3*a3;
    }
    sd[tid]=s; sq[tid]=s2; __syncthreads();
    for(int off=128; off>0; off>>=1){
        if(tid<off){ sd[tid]+=sd[tid+off]; sq[tid]+=sq[tid+off]; }
        __syncthreads();
    }
    if(tid==0){
        atomicAdd(&stats[256+c], sd[0]);
        atomicAdd(&stats[384+c], sq[0]);
    }
}

// ---------------- BN2 + ReLU -> f32 out (float4; finalizes stats2 sums inline)
__global__ __launch_bounds__(256) void k_bn_relu_out(const float* Hs, const float* stats, fp g, fp bb, float* out){
    int idx = blockIdx.x*256+threadIdx.x;       // 1,048,576 float4
    int c = (idx>>10)&127;
    float mean2 = stats[256+c] * (1.f/32768.f);
    float var2  = stats[384+c] * (1.f/32768.f) - mean2*mean2;
    float rs = rsqrtf(var2 + 1e-5f) * g[c];
    float sb = bb[c] - mean2*rs;
    float4 v = ((const float4*)Hs)[idx];
    float4 o;
    o.x = fmaxf(v.x*rs+sb, 0.f);
    o.y = fmaxf(v.y*rs+sb, 0.f);
    o.z = fmaxf(v.z*rs+sb, 0.f);
    o.w = fmaxf(v.w*rs+sb, 0.f);
    ((float4*)out)[idx] = o;
}

extern "C" void kernel_launch(void* const* d_in, const int* in_sizes, int n_in,
                              void* d_out, int out_size, void* d_ws, size_t ws_size,
                              hipStream_t stream){
    fp x1   = (fp)d_in[0];
    fp x2   = (fp)d_in[1];
    fp dw_w = (fp)d_in[2];  fp dw_b = (fp)d_in[3];
    fp pw_w = (fp)d_in[4];  fp pw_b = (fp)d_in[5];
    fp p_w  = (fp)d_in[6];  fp p_b  = (fp)d_in[7];
    fp m_w  = (fp)d_in[8];  fp m_b  = (fp)d_in[9];
    fp dcn_w= (fp)d_in[10];
    fp bn1g = (fp)d_in[11]; fp bn1b = (fp)d_in[12];
    fp dw2w = (fp)d_in[13]; fp dw2b = (fp)d_in[14];
    fp bn2g = (fp)d_in[15]; fp bn2b = (fp)d_in[16];

    float* ws  = (float*)d_ws;
    float* Bo  = ws;                    // (8,256,4096) = 8,388,608 f ; D reuses after k_pw
    float* Ccl = ws + 8388608;          // (8,4096,128) = 4,194,304 f ; Hs reuses after k_deform
    float* OM  = ws + 12582912;         // (8,27,4096)  =   884,736 f
    unsigned short* Wbf = (unsigned short*)(ws + 13467648);  // 147,456 bf16 (73,728 f)
    unsigned short* Wpm = (unsigned short*)(ws + 13541376);  //  36,864 bf16 (18,432 f)
    float* stats = ws + 13559808;       // 512 f (sum1, sq1, sum2, sq2)
    float* Wpwt  = ws + 13560320;       // 32,768 f (pw_w transposed [c][o])
    float* D   = Bo;                    // Bo dead after k_pw
    float* Hs  = Ccl;                   // Ccl dead after k_deform
    float* out = (float*)d_out;

    hipMemsetAsync(stats, 0, 512*sizeof(float), stream);
    k_prep         <<<848,   256, 0, stream>>>(dcn_w, p_w, m_w, pw_w, Wbf, Wpm, Wpwt);
    k_updw256      <<<2048,  256, 0, stream>>>(x1, x2, dw_w, dw_b, Bo);
    k_pw           <<<1024,  256, 0, stream>>>(Bo, Wpwt, pw_b, Ccl);
    k_offmask      <<<512,   256, 0, stream>>>(Ccl, Wpm, p_b, m_b, OM);
    k_deform       <<<1024,  256, 0, stream>>>(Ccl, OM, Wbf, D, stats);
    k_bngelu_dw128 <<<1024,  256, 0, stream>>>(D, stats, bn1g, bn1b, dw2w, dw2b, Hs);
    k_bn_relu_out  <<<4096,  256, 0, stream>>>(Hs, stats, bn2g, bn2b, out);
}